// Round 7
// baseline (1824.980 us; speedup 1.0000x reference)
//
#include <hip/hip_runtime.h>
#include <hip/hip_bf16.h>
#include <math.h>

typedef __attribute__((ext_vector_type(8))) _Float16 half8;
typedef __attribute__((ext_vector_type(4))) float f32x4;
typedef __attribute__((ext_vector_type(4))) unsigned int u32x4;

#define FDIM 128
#define EPSBN 1e-5f
#define HSCALE_INV 0.015625f   // h presented to MFMA as h/64
#define WSCALE 64.0f           // node-weight rows pre-scaled (exact pow2)

// ======== weight prep: node part Wn[i][c4][col512][kk] fp16, swizzled ========
__global__ void prep_wn(const float* __restrict__ Wf, const float* __restrict__ Ws,
                        _Float16* __restrict__ Wn) {
    int idx = blockIdx.x * 256 + threadIdx.x;
    const int total = 6 * 4 * 512 * 32;
    if (idx >= total) return;
    int kk = idx & 31;
    int col = (idx >> 5) & 511;
    int c4 = (idx >> 14) & 3;
    int i = idx >> 16;
    int which = col >> 8;
    int colc = col & 255;
    int p = (colc >> 4) & 1;
    int f = ((colc >> 5) << 4) | (colc & 15);
    int ksrc = c4 * 32 + (kk ^ ((colc & 3) << 3));
    int row = which * 128 + ksrc;
    size_t o = ((size_t)i * 297 + row) * 128 + f;
    float v = (p ? Ws[o] : Wf[o]) * WSCALE;
    Wn[idx] = (_Float16)v;
}

// ======== weight prep: ea part, register-fragment layout ========
__global__ void prep_wb2(const float* __restrict__ Wf, const float* __restrict__ Ws,
                         _Float16* __restrict__ Wb2) {
    int idx = blockIdx.x * 256 + threadIdx.x;
    const int total = 6 * 16384;
    if (idx >= total) return;
    int j = idx & 7;
    int l15 = (idx >> 3) & 15;
    int lhi = (idx >> 7) & 3;
    int cb = (idx >> 9) & 15;
    int c2 = (idx >> 13) & 1;
    int i = idx >> 14;
    int k = c2 * 32 + lhi * 8 + j;
    int colc = cb * 16 + l15;
    int p = (colc >> 4) & 1;
    int f = ((colc >> 5) << 4) | (colc & 15);
    float v = 0.0f;
    if (k < 41) {
        size_t o = ((size_t)i * 297 + 256 + k) * 128 + f;
        v = p ? Ws[o] : Wf[o];
    }
    Wb2[idx] = (_Float16)v;
}

// ======== sorting: hist -> scan -> scatter (packed src|dst, perm) ========
__global__ void hist_k(const int* __restrict__ dstI, int* __restrict__ cnt, int E) {
    int e = blockIdx.x * 256 + threadIdx.x;
    if (e < E) atomicAdd(&cnt[dstI[e]], 1);
}

__global__ void scan_k(const int* __restrict__ cnt, int* __restrict__ cursor, int N) {
    __shared__ int part[256];
    int t = threadIdx.x;
    int chunk = (N + 255) / 256;
    int lo = t * chunk, hi = lo + chunk; if (hi > N) hi = N;
    int s = 0;
    for (int i = lo; i < hi; ++i) s += cnt[i];
    part[t] = s;
    __syncthreads();
    for (int d = 1; d < 256; d <<= 1) {
        int v = (t >= d) ? part[t - d] : 0;
        __syncthreads();
        part[t] += v;
        __syncthreads();
    }
    int run = (t > 0) ? part[t - 1] : 0;
    for (int i = lo; i < hi; ++i) { cursor[i] = run; run += cnt[i]; }
}

__global__ void scatter_k(const int* __restrict__ srcI, const int* __restrict__ dstI,
                          int* __restrict__ cursor, unsigned* __restrict__ sdS,
                          int* __restrict__ perm, int E) {
    int e = blockIdx.x * 256 + threadIdx.x;
    if (e >= E) return;
    int d = dstI[e];
    int pos = atomicAdd(&cursor[d], 1);
    sdS[pos] = (unsigned)srcI[e] | ((unsigned)d << 16);
    perm[pos] = e;
}

// ======== embed ========
__global__ void embed_k(const float* __restrict__ x, const float* __restrict__ W,
                        const float* __restrict__ b, float* __restrict__ h, int N) {
    int n = blockIdx.x * 2 + (threadIdx.x >> 7);
    int f = threadIdx.x & 127;
    if (n >= N) return;
    float acc = b[f];
    const float* xr = x + (size_t)n * 98;
    #pragma unroll 7
    for (int k = 0; k < 98; ++k) acc = fmaf(xr[k], W[k * 128 + f], acc);
    h[(size_t)n * 128 + f] = acc;
}

// ======== node GEMM: Pd/Ps = h @ Wtop/Wmid (stages h f32 -> fp16/64) ========
__global__ __launch_bounds__(256, 2)
void node_gemm(const float* __restrict__ h, const _Float16* __restrict__ WnL,
               float* __restrict__ Pd, float* __restrict__ Ps, int N) {
    __shared__ __align__(16) _Float16 ht[32 * 128];
    __shared__ __align__(16) _Float16 wt[512 * 32];
    const int tid = threadIdx.x;
    const int nb = blockIdx.x * 32;

    {   // 8 threads/row, 16 floats each -> fp16*HSCALE_INV -> 2x16B LDS units
        int e = tid >> 3, t = tid & 7;
        int node = nb + e; if (node >= N) node = N - 1;
        const float* src = h + (size_t)node * 128 + t * 16;
        int swz = (e & 7) << 4;
        __align__(16) _Float16 tmp[16];
        #pragma unroll
        for (int u = 0; u < 16; ++u) tmp[u] = (_Float16)(src[u] * HSCALE_INV);
        *(u32x4*)((char*)ht + e * 256 + (((2 * t) * 16) ^ swz)) = *(u32x4*)tmp;
        *(u32x4*)((char*)ht + e * 256 + (((2 * t + 1) * 16) ^ swz)) = *(u32x4*)(tmp + 8);
    }

    f32x4 acc[2][8];
    #pragma unroll
    for (int m = 0; m < 2; ++m)
        #pragma unroll
        for (int n = 0; n < 8; ++n) acc[m][n] = (f32x4){0.f, 0.f, 0.f, 0.f};

    const int wid = tid >> 6;
    const int lane = tid & 63;
    const int l15 = lane & 15;
    const int lhi = lane >> 4;
    const int swzA = (l15 & 7) << 4;

    for (int c4 = 0; c4 < 4; ++c4) {
        const u32x4* gw = (const u32x4*)(WnL + (size_t)c4 * 512 * 32);
        #pragma unroll
        for (int j = 0; j < 8; ++j) ((u32x4*)wt)[tid + 256 * j] = gw[tid + 256 * j];
        __syncthreads();

        half8 a[2];
        #pragma unroll
        for (int m = 0; m < 2; ++m) {
            int r = m * 16 + l15;
            a[m] = *(const half8*)((const char*)ht + r * 256 + ((c4 * 64 + lhi * 16) ^ swzA));
        }
        #pragma unroll
        for (int n = 0; n < 8; ++n) {
            int col = wid * 128 + n * 16 + l15;
            half8 b = *(const half8*)((const char*)wt + col * 64 + ((lhi * 16) ^ ((col & 3) << 4)));
            #pragma unroll
            for (int m = 0; m < 2; ++m)
                acc[m][n] = __builtin_amdgcn_mfma_f32_16x16x32_f16(a[m], b, acc[m][n], 0, 0, 0);
        }
        __syncthreads();
    }

    #pragma unroll
    for (int m = 0; m < 2; ++m) {
        #pragma unroll
        for (int n = 0; n < 8; ++n) {
            int col512 = wid * 128 + n * 16 + l15;
            float* base = (col512 < 256) ? Pd : Ps;
            int c = col512 & 255;
            #pragma unroll
            for (int j = 0; j < 4; ++j) {
                int node = nb + m * 16 + lhi * 4 + j;
                if (node < N) base[(size_t)node * 256 + c] = acc[m][n][j];
            }
        }
    }
}

// ======== edge kernel v3: sorted edges, in-kernel ea gather, LDS slot agg ========
__global__ __launch_bounds__(256, 3)
void edge_v3(const float* __restrict__ ea, const int* __restrict__ perm,
             const unsigned* __restrict__ sdS,
             const _Float16* __restrict__ WbL,     // [2][16][4][16][8] fragments
             const float* __restrict__ Pd, const float* __restrict__ Ps,
             const float* __restrict__ biasF, const float* __restrict__ biasS,
             float* __restrict__ agg) {
    __shared__ __align__(16) _Float16 eat[64 * 64];   // 8 KB swizzled
    __shared__ float lacc[64 * 128];                  // 32 KB slot accumulator
    __shared__ int srcl[64], dstl[64], slotl[64], sdstl[64];
    __shared__ int nslots_s;

    const int tid = threadIdx.x;
    const int eb = blockIdx.x * 64;

    #pragma unroll
    for (int i = 0; i < 32; ++i) lacc[tid + 256 * i] = 0.0f;

    if (tid < 64) {          // wave 0: unpack + dst run -> slots (INCLUSIVE count)
        unsigned sd = sdS[eb + tid];
        int d = (int)(sd >> 16);
        srcl[tid] = (int)(sd & 0xFFFFu);
        dstl[tid] = d;
        int dp = __shfl_up(d, 1);
        int neq = (tid > 0 && d != dp) ? 1 : 0;
        unsigned long long mask = __ballot(neq);
        int s = (int)__popcll(mask & ((1ull << tid) - 1ull)) + neq;  // inclusive
        slotl[tid] = s;
        if (neq || tid == 0) sdstl[s] = d;
        if (tid == 63) nslots_s = s + 1;
    }

    {   // stage ea tile: 8 threads/edge, unit q = 8 fp16 cols, gather via perm
        #pragma unroll
        for (int pass = 0; pass < 2; ++pass) {
            int u = tid + pass * 256;            // 0..511
            int e = u >> 3, q = u & 7;
            int oe = perm[eb + e];
            const float* row = ea + (size_t)oe * 41 + q * 8;
            __align__(16) _Float16 tmp[8];
            #pragma unroll
            for (int c = 0; c < 8; ++c) {
                int col = q * 8 + c;
                tmp[c] = (col < 41) ? (_Float16)row[c] : (_Float16)0.f;
            }
            *(u32x4*)((char*)eat + e * 128 + ((q * 16) ^ ((e & 7) << 4))) = *(u32x4*)tmp;
        }
    }
    __syncthreads();

    f32x4 acc[4][4];
    #pragma unroll
    for (int m = 0; m < 4; ++m)
        #pragma unroll
        for (int n = 0; n < 4; ++n) acc[m][n] = (f32x4){0.f, 0.f, 0.f, 0.f};

    const int wid = tid >> 6;
    const int lane = tid & 63;
    const int l15 = lane & 15;
    const int lhi = lane >> 4;

    #pragma unroll
    for (int c2 = 0; c2 < 2; ++c2) {
        half8 a[4];
        #pragma unroll
        for (int m = 0; m < 4; ++m) {
            int r = m * 16 + l15;
            a[m] = *(const half8*)((const char*)eat + r * 128 +
                                   ((c2 * 64 + lhi * 16) ^ ((r & 7) << 4)));
        }
        #pragma unroll
        for (int n = 0; n < 4; ++n) {
            int cb = wid * 4 + n;
            const half8 b = *(const half8*)(WbL +
                            ((((size_t)c2 * 16 + cb) * 4 + lhi) * 16 + l15) * 8);
            #pragma unroll
            for (int m = 0; m < 4; ++m)
                acc[m][n] = __builtin_amdgcn_mfma_f32_16x16x32_f16(a[m], b, acc[m][n], 0, 0, 0);
        }
    }

    // epilogue: gate and accumulate into LDS slots
    const int cF0 = wid * 64 + l15;
    const int feat0 = wid * 32 + l15;
    const float bF0 = biasF[feat0], bF1 = biasF[feat0 + 16];
    const float bS0 = biasS[feat0], bS1 = biasS[feat0 + 16];

    #pragma unroll
    for (int m = 0; m < 4; ++m) {
        #pragma unroll
        for (int j = 0; j < 4; ++j) {
            int r = m * 16 + lhi * 4 + j;
            const float* pd = Pd + (size_t)dstl[r] * 256;
            const float* ps = Ps + (size_t)srcl[r] * 256;
            int s = slotl[r];
            #pragma unroll
            for (int p = 0; p < 2; ++p) {
                int cF = cF0 + 32 * p;
                float fp = acc[m][2 * p][j] + pd[cF] + ps[cF] + (p ? bF1 : bF0);
                float sp = acc[m][2 * p + 1][j] + pd[cF + 16] + ps[cF + 16] + (p ? bS1 : bS0);
                float sig = 1.0f / (1.0f + __expf(-fp));
                float spl = fmaxf(sp, 0.0f) + __logf(1.0f + __expf(-fabsf(sp)));
                atomicAdd(&lacc[s * 128 + feat0 + 16 * p], sig * spl);
            }
        }
    }
    __syncthreads();

    // flush slots to global agg
    int ns = nslots_s;
    int f = tid & 127;
    for (int s = tid >> 7; s < ns; s += 2)
        atomicAdd(&agg[(size_t)sdstl[s] * 128 + f], lacc[s * 128 + f]);
}

// ======== BN_in + residual + BN_out (+outer residual) ========
__global__ void node_bn(const float* __restrict__ agg, float* __restrict__ h,
                        const float* __restrict__ gin, const float* __restrict__ bin,
                        const float* __restrict__ min_, const float* __restrict__ vin,
                        const float* __restrict__ gout, const float* __restrict__ bout,
                        const float* __restrict__ mout, const float* __restrict__ vout,
                        int addres, int n128) {
    int idx = blockIdx.x * 256 + threadIdx.x;
    if (idx >= n128) return;
    int f = idx & 127;
    float a = agg[idx];
    a = (a - min_[f]) * (gin[f] / sqrtf(vin[f] + EPSBN)) + bin[f];
    float hv = h[idx];
    float xo = a + hv;
    xo = (xo - mout[f]) * (gout[f] / sqrtf(vout[f] + EPSBN)) + bout[f];
    if (addres) xo += hv;
    h[idx] = xo;
}

// ======== pool ========
__global__ void pool_k(const float* __restrict__ h, const int* __restrict__ batch,
                       float* __restrict__ sums, unsigned* __restrict__ maxs,
                       float* __restrict__ counts, int N) {
    int idx = blockIdx.x * 256 + threadIdx.x;
    if (idx >= N * 128) return;
    int n = idx >> 7, f = idx & 127;
    int g = batch[n];
    float v = h[idx];
    atomicAdd(&sums[g * 128 + f], v);
    unsigned u = __float_as_uint(v);
    unsigned key = (u & 0x80000000u) ? ~u : (u | 0x80000000u);
    atomicMax(&maxs[g * 128 + f], key);
    if (f == 0) atomicAdd(&counts[g], 1.0f);
}

// ======== heads ========
__global__ __launch_bounds__(256)
void head_k(const float* __restrict__ sums, const unsigned* __restrict__ maxs,
            const float* __restrict__ counts,
            const float* __restrict__ pW, const float* __restrict__ pb,
            const float* __restrict__ f1W, const float* __restrict__ f1b,
            const float* __restrict__ f2W, const float* __restrict__ f2b,
            const float* __restrict__ f3W, const float* __restrict__ f3b,
            const float* __restrict__ d1W, const float* __restrict__ d1b,
            const float* __restrict__ d2W, const float* __restrict__ d2b,
            float* __restrict__ out) {
    __shared__ float xp[256], emb[128], s1[256], s2[128], dd[256];
    int g = blockIdx.x, t = threadIdx.x;
    float cnt = counts[g];
    if (t < 128) {
        float mean = sums[g * 128 + t] / fmaxf(cnt, 1.0f);
        float mx = 0.0f;
        if (cnt > 0.0f) {
            unsigned key = maxs[g * 128 + t];
            unsigned u = (key & 0x80000000u) ? (key & 0x7fffffffu) : ~key;
            mx = __uint_as_float(u);
            if (!isfinite(mx)) mx = 0.0f;
        }
        xp[t] = mean;
        xp[128 + t] = mx;
    }
    __syncthreads();
    if (t < 128) {
        float a = pb[t];
        for (int k = 0; k < 256; ++k) a = fmaf(xp[k], pW[k * 128 + t], a);
        emb[t] = fmaxf(a, 0.0f);
    }
    __syncthreads();
    {
        float a = f1b[t];
        for (int k = 0; k < 128; ++k) a = fmaf(emb[k], f1W[k * 256 + t], a);
        s1[t] = a / (1.0f + __expf(-a));
    }
    __syncthreads();
    if (t < 128) {
        float a = f2b[t];
        for (int k = 0; k < 256; ++k) a = fmaf(s1[k], f2W[k * 128 + t], a);
        s2[t] = a / (1.0f + __expf(-a));
    }
    {
        float a = d1b[t];
        for (int k = 0; k < 128; ++k) a = fmaf(emb[k], d1W[k * 256 + t], a);
        dd[t] = a / (1.0f + __expf(-a));
    }
    __syncthreads();
    if (t == 0) {
        float a = f3b[0];
        for (int k = 0; k < 128; ++k) a = fmaf(s2[k], f3W[k], a);
        out[g] = a;
    }
    for (int o = t; o < 384; o += 256) {
        float a = d2b[o];
        for (int k = 0; k < 256; ++k) a = fmaf(dd[k], d2W[k * 384 + o], a);
        out[128 + (size_t)g * 384 + o] = a;
    }
}

extern "C" void kernel_launch(void* const* d_in, const int* in_sizes, int n_in,
                              void* d_out, int out_size, void* d_ws, size_t ws_size,
                              hipStream_t stream) {
    const float* x       = (const float*)d_in[0];
    const int*   eidx    = (const int*)d_in[1];
    const float* ea      = (const float*)d_in[2];
    const int*   batch   = (const int*)d_in[3];
    const float* embW    = (const float*)d_in[4];
    const float* embB    = (const float*)d_in[5];
    const float* convWf  = (const float*)d_in[6];
    const float* convbf  = (const float*)d_in[7];
    const float* convWs  = (const float*)d_in[8];
    const float* convbs  = (const float*)d_in[9];
    const float* bing    = (const float*)d_in[10];
    const float* binb    = (const float*)d_in[11];
    const float* binm    = (const float*)d_in[12];
    const float* binv    = (const float*)d_in[13];
    const float* bog     = (const float*)d_in[14];
    const float* bob     = (const float*)d_in[15];
    const float* bom     = (const float*)d_in[16];
    const float* bov     = (const float*)d_in[17];
    const float* pW      = (const float*)d_in[18];
    const float* pb      = (const float*)d_in[19];
    const float* f1W     = (const float*)d_in[20];
    const float* f1b     = (const float*)d_in[21];
    const float* f2W     = (const float*)d_in[22];
    const float* f2b     = (const float*)d_in[23];
    const float* f3W     = (const float*)d_in[24];
    const float* f3b     = (const float*)d_in[25];
    const float* d1W     = (const float*)d_in[26];
    const float* d1b     = (const float*)d_in[27];
    const float* d2W     = (const float*)d_in[28];
    const float* d2b     = (const float*)d_in[29];

    const int N = in_sizes[0] / 98;
    const int E = in_sizes[1] / 2;
    const int* srcI = eidx;
    const int* dstI = eidx + E;

    // workspace layout (total 65.1 MB)
    char* ws = (char*)d_ws;
    float* h        = (float*)(ws);                     // 10,240,000
    float* agg      = (float*)(ws + 10240000);          // 10,240,000
    float* Pd       = (float*)(ws + 20480000);          // 20,480,000
    float* Ps       = (float*)(ws + 40960000);          // 20,480,000
    _Float16* Wn    = (_Float16*)(ws + 61440000);       //    786,432
    _Float16* Wb2   = (_Float16*)(ws + 62226432);       //    196,608
    float* sums     = (float*)(ws + 62423040);          //     65,536
    unsigned* maxs  = (unsigned*)(ws + 62488576);       //     65,536
    float* gcnt     = (float*)(ws + 62554112);          //        512
    unsigned* sdS   = (unsigned*)(ws + 62554624);       //  1,280,000
    int* perm       = (int*)(ws + 63834624);            //  1,280,000  -> end 65,114,624
    // sort scratch aliased into Pd (dead before first node_gemm)
    int* nodeCnt    = (int*)(ws + 20480000);
    int* cursor     = nodeCnt + N;

    prep_wn<<<(6 * 4 * 512 * 32) / 256, 256, 0, stream>>>(convWf, convWs, Wn);
    prep_wb2<<<(6 * 16384 + 255) / 256, 256, 0, stream>>>(convWf, convWs, Wb2);
    hipMemsetAsync(nodeCnt, 0, (size_t)N * 4, stream);
    hist_k<<<(E + 255) / 256, 256, 0, stream>>>(dstI, nodeCnt, E);
    scan_k<<<1, 256, 0, stream>>>(nodeCnt, cursor, N);
    scatter_k<<<(E + 255) / 256, 256, 0, stream>>>(srcI, dstI, cursor, sdS, perm, E);
    embed_k<<<(N + 1) / 2, 256, 0, stream>>>(x, embW, embB, h, N);

    const int n128 = N * 128;
    const int nblk = (N + 31) / 32;
    for (int i = 0; i < 6; ++i) {
        node_gemm<<<nblk, 256, 0, stream>>>(h, Wn + (size_t)i * 4 * 512 * 32, Pd, Ps, N);
        hipMemsetAsync(agg, 0, (size_t)n128 * 4, stream);
        edge_v3<<<E / 64, 256, 0, stream>>>(ea, perm, sdS,
                                            Wb2 + (size_t)i * 16384,
                                            Pd, Ps, convbf + i * 128, convbs + i * 128, agg);
        node_bn<<<(n128 + 255) / 256, 256, 0, stream>>>(
            agg, h,
            bing + i * 128, binb + i * 128, binm + i * 128, binv + i * 128,
            bog + i * 128, bob + i * 128, bom + i * 128, bov + i * 128,
            (i > 0) ? 1 : 0, n128);
    }

    hipMemsetAsync(sums, 0, 65536 + 65536 + 512, stream);
    pool_k<<<(n128 + 255) / 256, 256, 0, stream>>>(h, batch, sums, maxs, gcnt, N);
    head_k<<<128, 256, 0, stream>>>(sums, maxs, gcnt, pW, pb,
                                    f1W, f1b, f2W, f2b, f3W, f3b,
                                    d1W, d1b, d2W, d2b, (float*)d_out);
}

// Round 8
// 1797.559 us; speedup vs baseline: 1.0153x; 1.0153x over previous
//
#include <hip/hip_runtime.h>
#include <hip/hip_bf16.h>
#include <math.h>

typedef __attribute__((ext_vector_type(8))) _Float16 half8;
typedef __attribute__((ext_vector_type(4))) float f32x4;
typedef __attribute__((ext_vector_type(4))) unsigned int u32x4;

#define FDIM 128
#define EPSBN 1e-5f
#define HSCALE_INV 0.015625f   // h presented to MFMA as h/64
#define WSCALE 64.0f           // node-weight rows pre-scaled (exact pow2)

// ======== weight prep: node part Wn[i][c4][col512][kk] fp16, swizzled ========
__global__ void prep_wn(const float* __restrict__ Wf, const float* __restrict__ Ws,
                        _Float16* __restrict__ Wn) {
    int idx = blockIdx.x * 256 + threadIdx.x;
    const int total = 6 * 4 * 512 * 32;
    if (idx >= total) return;
    int kk = idx & 31;
    int col = (idx >> 5) & 511;
    int c4 = (idx >> 14) & 3;
    int i = idx >> 16;
    int which = col >> 8;
    int colc = col & 255;
    int p = (colc >> 4) & 1;
    int f = ((colc >> 5) << 4) | (colc & 15);
    int ksrc = c4 * 32 + (kk ^ ((colc & 3) << 3));
    int row = which * 128 + ksrc;
    size_t o = ((size_t)i * 297 + row) * 128 + f;
    float v = (p ? Ws[o] : Wf[o]) * WSCALE;
    Wn[idx] = (_Float16)v;
}

// ======== weight prep: ea part, register-fragment layout ========
// Wb2[i][c2][cb][lhi][l15][j] = W[256 + c2*32+lhi*8+j][colmap(cb*16+l15)]
__global__ void prep_wb2(const float* __restrict__ Wf, const float* __restrict__ Ws,
                         _Float16* __restrict__ Wb2) {
    int idx = blockIdx.x * 256 + threadIdx.x;
    const int total = 6 * 16384;
    if (idx >= total) return;
    int j = idx & 7;
    int l15 = (idx >> 3) & 15;
    int lhi = (idx >> 7) & 3;
    int cb = (idx >> 9) & 15;
    int c2 = (idx >> 13) & 1;
    int i = idx >> 14;
    int k = c2 * 32 + lhi * 8 + j;
    int colc = cb * 16 + l15;
    int p = (colc >> 4) & 1;
    int f = ((colc >> 5) << 4) | (colc & 15);
    float v = 0.0f;
    if (k < 41) {
        size_t o = ((size_t)i * 297 + 256 + k) * 128 + f;
        v = p ? Ws[o] : Wf[o];
    }
    Wb2[idx] = (_Float16)v;
}

// ======== sorting: hist -> scan -> scatter -> permute ea ========
__global__ void hist_k(const int* __restrict__ dstI, int* __restrict__ cnt, int E) {
    int e = blockIdx.x * 256 + threadIdx.x;
    if (e < E) atomicAdd(&cnt[dstI[e]], 1);
}

__global__ void scan_k(const int* __restrict__ cnt, int* __restrict__ cursor, int N) {
    __shared__ int part[256];
    int t = threadIdx.x;
    int chunk = (N + 255) / 256;
    int lo = t * chunk, hi = lo + chunk; if (hi > N) hi = N;
    int s = 0;
    for (int i = lo; i < hi; ++i) s += cnt[i];
    part[t] = s;
    __syncthreads();
    for (int d = 1; d < 256; d <<= 1) {
        int v = (t >= d) ? part[t - d] : 0;
        __syncthreads();
        part[t] += v;
        __syncthreads();
    }
    int run = (t > 0) ? part[t - 1] : 0;
    for (int i = lo; i < hi; ++i) { cursor[i] = run; run += cnt[i]; }
}

__global__ void scatter_k(const int* __restrict__ srcI, const int* __restrict__ dstI,
                          int* __restrict__ cursor, unsigned* __restrict__ sdS,
                          int* __restrict__ perm, int E) {
    int e = blockIdx.x * 256 + threadIdx.x;
    if (e >= E) return;
    int d = dstI[e];
    int pos = atomicAdd(&cursor[d], 1);
    sdS[pos] = (unsigned)srcI[e] | ((unsigned)d << 16);
    perm[pos] = e;
}

__global__ void permute_ea(const float* __restrict__ ea, const int* __restrict__ perm,
                           _Float16* __restrict__ eaH, int E) {
    int pos = blockIdx.x * 4 + (threadIdx.x >> 6);
    int c = threadIdx.x & 63;
    if (pos >= E) return;
    int e = perm[pos];
    float v = (c < 41) ? ea[(size_t)e * 41 + c] : 0.0f;
    eaH[(size_t)pos * 64 + c] = (_Float16)v;
}

// ======== embed ========
__global__ void embed_k(const float* __restrict__ x, const float* __restrict__ W,
                        const float* __restrict__ b, float* __restrict__ h, int N) {
    int n = blockIdx.x * 2 + (threadIdx.x >> 7);
    int f = threadIdx.x & 127;
    if (n >= N) return;
    float acc = b[f];
    const float* xr = x + (size_t)n * 98;
    #pragma unroll 7
    for (int k = 0; k < 98; ++k) acc = fmaf(xr[k], W[k * 128 + f], acc);
    h[(size_t)n * 128 + f] = acc;
}

// ======== node GEMM: Pd/Ps = h @ Wtop/Wmid (stages h f32 -> fp16/64) ========
__global__ __launch_bounds__(256, 2)
void node_gemm(const float* __restrict__ h, const _Float16* __restrict__ WnL,
               float* __restrict__ Pd, float* __restrict__ Ps, int N) {
    __shared__ __align__(16) _Float16 ht[32 * 128];
    __shared__ __align__(16) _Float16 wt[512 * 32];
    const int tid = threadIdx.x;
    const int nb = blockIdx.x * 32;

    {
        int e = tid >> 3, t = tid & 7;
        int node = nb + e; if (node >= N) node = N - 1;
        const float* src = h + (size_t)node * 128 + t * 16;
        int swz = (e & 7) << 4;
        __align__(16) _Float16 tmp[16];
        #pragma unroll
        for (int u = 0; u < 16; ++u) tmp[u] = (_Float16)(src[u] * HSCALE_INV);
        *(u32x4*)((char*)ht + e * 256 + (((2 * t) * 16) ^ swz)) = *(u32x4*)tmp;
        *(u32x4*)((char*)ht + e * 256 + (((2 * t + 1) * 16) ^ swz)) = *(u32x4*)(tmp + 8);
    }

    f32x4 acc[2][8];
    #pragma unroll
    for (int m = 0; m < 2; ++m)
        #pragma unroll
        for (int n = 0; n < 8; ++n) acc[m][n] = (f32x4){0.f, 0.f, 0.f, 0.f};

    const int wid = tid >> 6;
    const int lane = tid & 63;
    const int l15 = lane & 15;
    const int lhi = lane >> 4;
    const int swzA = (l15 & 7) << 4;

    for (int c4 = 0; c4 < 4; ++c4) {
        const u32x4* gw = (const u32x4*)(WnL + (size_t)c4 * 512 * 32);
        #pragma unroll
        for (int j = 0; j < 8; ++j) ((u32x4*)wt)[tid + 256 * j] = gw[tid + 256 * j];
        __syncthreads();

        half8 a[2];
        #pragma unroll
        for (int m = 0; m < 2; ++m) {
            int r = m * 16 + l15;
            a[m] = *(const half8*)((const char*)ht + r * 256 + ((c4 * 64 + lhi * 16) ^ swzA));
        }
        #pragma unroll
        for (int n = 0; n < 8; ++n) {
            int col = wid * 128 + n * 16 + l15;
            half8 b = *(const half8*)((const char*)wt + col * 64 + ((lhi * 16) ^ ((col & 3) << 4)));
            #pragma unroll
            for (int m = 0; m < 2; ++m)
                acc[m][n] = __builtin_amdgcn_mfma_f32_16x16x32_f16(a[m], b, acc[m][n], 0, 0, 0);
        }
        __syncthreads();
    }

    #pragma unroll
    for (int m = 0; m < 2; ++m) {
        #pragma unroll
        for (int n = 0; n < 8; ++n) {
            int col512 = wid * 128 + n * 16 + l15;
            float* base = (col512 < 256) ? Pd : Ps;
            int c = col512 & 255;
            #pragma unroll
            for (int j = 0; j < 4; ++j) {
                int node = nb + m * 16 + lhi * 4 + j;
                if (node < N) base[(size_t)node * 256 + c] = acc[m][n][j];
            }
        }
    }
}

// ======== edge kernel v4: direct-register A-frags from contiguous eaH ========
__global__ __launch_bounds__(256, 4)
void edge_v4(const _Float16* __restrict__ eaH,
             const unsigned* __restrict__ sdS,
             const _Float16* __restrict__ WbL,     // [2][16][4][16][8] fragments
             const float* __restrict__ Pd, const float* __restrict__ Ps,
             const float* __restrict__ biasF, const float* __restrict__ biasS,
             float* __restrict__ agg) {
    __shared__ float lacc[64 * 128];                  // 32 KB slot accumulator
    __shared__ int srcl[64], dstl[64], slotl[64], sdstl[64];
    __shared__ int nslots_s;

    const int tid = threadIdx.x;
    const int eb = blockIdx.x * 64;

    #pragma unroll
    for (int i = 0; i < 32; ++i) lacc[tid + 256 * i] = 0.0f;

    if (tid < 64) {          // wave 0: unpack + dst run -> slots (inclusive count)
        unsigned sd = sdS[eb + tid];
        int d = (int)(sd >> 16);
        srcl[tid] = (int)(sd & 0xFFFFu);
        dstl[tid] = d;
        int dp = __shfl_up(d, 1);
        int neq = (tid > 0 && d != dp) ? 1 : 0;
        unsigned long long mask = __ballot(neq);
        int s = (int)__popcll(mask & ((1ull << tid) - 1ull)) + neq;
        slotl[tid] = s;
        if (neq || tid == 0) sdstl[s] = d;
        if (tid == 63) nslots_s = s + 1;
    }
    __syncthreads();

    const int wid = tid >> 6;
    const int lane = tid & 63;
    const int l15 = lane & 15;
    const int lhi = lane >> 4;

    f32x4 acc[4][4];
    #pragma unroll
    for (int m = 0; m < 4; ++m)
        #pragma unroll
        for (int n = 0; n < 4; ++n) acc[m][n] = (f32x4){0.f, 0.f, 0.f, 0.f};

    // K=64 GEMM, A-frags straight from global (block rows are contiguous in eaH)
    #pragma unroll
    for (int c2 = 0; c2 < 2; ++c2) {
        half8 a[4];
        #pragma unroll
        for (int m = 0; m < 4; ++m) {
            int r = m * 16 + l15;
            a[m] = *(const half8*)(eaH + (size_t)(eb + r) * 64 + c2 * 32 + lhi * 8);
        }
        #pragma unroll
        for (int n = 0; n < 4; ++n) {
            int cb = wid * 4 + n;
            const half8 b = *(const half8*)(WbL +
                            ((((size_t)c2 * 16 + cb) * 4 + lhi) * 16 + l15) * 8);
            #pragma unroll
            for (int m = 0; m < 4; ++m)
                acc[m][n] = __builtin_amdgcn_mfma_f32_16x16x32_f16(a[m], b, acc[m][n], 0, 0, 0);
        }
    }

    // epilogue: + Pd[dst] + Ps[src] + bias ; gate ; accumulate into LDS slots
    const int cF0 = wid * 64 + l15;
    const int feat0 = wid * 32 + l15;
    const float bF0 = biasF[feat0], bF1 = biasF[feat0 + 16];
    const float bS0 = biasS[feat0], bS1 = biasS[feat0 + 16];

    #pragma unroll
    for (int m = 0; m < 4; ++m) {
        #pragma unroll
        for (int j = 0; j < 4; ++j) {
            int r = m * 16 + lhi * 4 + j;
            const float* pd = Pd + (size_t)dstl[r] * 256;
            const float* ps = Ps + (size_t)srcl[r] * 256;
            int s = slotl[r];
            #pragma unroll
            for (int p = 0; p < 2; ++p) {
                int cF = cF0 + 32 * p;
                float fp = acc[m][2 * p][j] + pd[cF] + ps[cF] + (p ? bF1 : bF0);
                float sp = acc[m][2 * p + 1][j] + pd[cF + 16] + ps[cF + 16] + (p ? bS1 : bS0);
                float sig = 1.0f / (1.0f + __expf(-fp));
                float spl = fmaxf(sp, 0.0f) + __logf(1.0f + __expf(-fabsf(sp)));
                atomicAdd(&lacc[s * 128 + feat0 + 16 * p], sig * spl);
            }
        }
    }
    __syncthreads();

    int ns = nslots_s;
    int f = tid & 127;
    for (int s = tid >> 7; s < ns; s += 2)
        atomicAdd(&agg[(size_t)sdstl[s] * 128 + f], lacc[s * 128 + f]);
}

// ======== BN_in + residual + BN_out (+outer residual) ========
__global__ void node_bn(const float* __restrict__ agg, float* __restrict__ h,
                        const float* __restrict__ gin, const float* __restrict__ bin,
                        const float* __restrict__ min_, const float* __restrict__ vin,
                        const float* __restrict__ gout, const float* __restrict__ bout,
                        const float* __restrict__ mout, const float* __restrict__ vout,
                        int addres, int n128) {
    int idx = blockIdx.x * 256 + threadIdx.x;
    if (idx >= n128) return;
    int f = idx & 127;
    float a = agg[idx];
    a = (a - min_[f]) * (gin[f] / sqrtf(vin[f] + EPSBN)) + bin[f];
    float hv = h[idx];
    float xo = a + hv;
    xo = (xo - mout[f]) * (gout[f] / sqrtf(vout[f] + EPSBN)) + bout[f];
    if (addres) xo += hv;
    h[idx] = xo;
}

// ======== pool ========
__global__ void pool_k(const float* __restrict__ h, const int* __restrict__ batch,
                       float* __restrict__ sums, unsigned* __restrict__ maxs,
                       float* __restrict__ counts, int N) {
    int idx = blockIdx.x * 256 + threadIdx.x;
    if (idx >= N * 128) return;
    int n = idx >> 7, f = idx & 127;
    int g = batch[n];
    float v = h[idx];
    atomicAdd(&sums[g * 128 + f], v);
    unsigned u = __float_as_uint(v);
    unsigned key = (u & 0x80000000u) ? ~u : (u | 0x80000000u);
    atomicMax(&maxs[g * 128 + f], key);
    if (f == 0) atomicAdd(&counts[g], 1.0f);
}

// ======== heads ========
__global__ __launch_bounds__(256)
void head_k(const float* __restrict__ sums, const unsigned* __restrict__ maxs,
            const float* __restrict__ counts,
            const float* __restrict__ pW, const float* __restrict__ pb,
            const float* __restrict__ f1W, const float* __restrict__ f1b,
            const float* __restrict__ f2W, const float* __restrict__ f2b,
            const float* __restrict__ f3W, const float* __restrict__ f3b,
            const float* __restrict__ d1W, const float* __restrict__ d1b,
            const float* __restrict__ d2W, const float* __restrict__ d2b,
            float* __restrict__ out) {
    __shared__ float xp[256], emb[128], s1[256], s2[128], dd[256];
    int g = blockIdx.x, t = threadIdx.x;
    float cnt = counts[g];
    if (t < 128) {
        float mean = sums[g * 128 + t] / fmaxf(cnt, 1.0f);
        float mx = 0.0f;
        if (cnt > 0.0f) {
            unsigned key = maxs[g * 128 + t];
            unsigned u = (key & 0x80000000u) ? (key & 0x7fffffffu) : ~key;
            mx = __uint_as_float(u);
            if (!isfinite(mx)) mx = 0.0f;
        }
        xp[t] = mean;
        xp[128 + t] = mx;
    }
    __syncthreads();
    if (t < 128) {
        float a = pb[t];
        for (int k = 0; k < 256; ++k) a = fmaf(xp[k], pW[k * 128 + t], a);
        emb[t] = fmaxf(a, 0.0f);
    }
    __syncthreads();
    {
        float a = f1b[t];
        for (int k = 0; k < 128; ++k) a = fmaf(emb[k], f1W[k * 256 + t], a);
        s1[t] = a / (1.0f + __expf(-a));
    }
    __syncthreads();
    if (t < 128) {
        float a = f2b[t];
        for (int k = 0; k < 256; ++k) a = fmaf(s1[k], f2W[k * 128 + t], a);
        s2[t] = a / (1.0f + __expf(-a));
    }
    {
        float a = d1b[t];
        for (int k = 0; k < 128; ++k) a = fmaf(emb[k], d1W[k * 256 + t], a);
        dd[t] = a / (1.0f + __expf(-a));
    }
    __syncthreads();
    if (t == 0) {
        float a = f3b[0];
        for (int k = 0; k < 128; ++k) a = fmaf(s2[k], f3W[k], a);
        out[g] = a;
    }
    for (int o = t; o < 384; o += 256) {
        float a = d2b[o];
        for (int k = 0; k < 256; ++k) a = fmaf(dd[k], d2W[k * 384 + o], a);
        out[128 + (size_t)g * 384 + o] = a;
    }
}

extern "C" void kernel_launch(void* const* d_in, const int* in_sizes, int n_in,
                              void* d_out, int out_size, void* d_ws, size_t ws_size,
                              hipStream_t stream) {
    const float* x       = (const float*)d_in[0];
    const int*   eidx    = (const int*)d_in[1];
    const float* ea      = (const float*)d_in[2];
    const int*   batch   = (const int*)d_in[3];
    const float* embW    = (const float*)d_in[4];
    const float* embB    = (const float*)d_in[5];
    const float* convWf  = (const float*)d_in[6];
    const float* convbf  = (const float*)d_in[7];
    const float* convWs  = (const float*)d_in[8];
    const float* convbs  = (const float*)d_in[9];
    const float* bing    = (const float*)d_in[10];
    const float* binb    = (const float*)d_in[11];
    const float* binm    = (const float*)d_in[12];
    const float* binv    = (const float*)d_in[13];
    const float* bog     = (const float*)d_in[14];
    const float* bob     = (const float*)d_in[15];
    const float* bom     = (const float*)d_in[16];
    const float* bov     = (const float*)d_in[17];
    const float* pW      = (const float*)d_in[18];
    const float* pb      = (const float*)d_in[19];
    const float* f1W     = (const float*)d_in[20];
    const float* f1b     = (const float*)d_in[21];
    const float* f2W     = (const float*)d_in[22];
    const float* f2b     = (const float*)d_in[23];
    const float* f3W     = (const float*)d_in[24];
    const float* f3b     = (const float*)d_in[25];
    const float* d1W     = (const float*)d_in[26];
    const float* d1b     = (const float*)d_in[27];
    const float* d2W     = (const float*)d_in[28];
    const float* d2b     = (const float*)d_in[29];

    const int N = in_sizes[0] / 98;
    const int E = in_sizes[1] / 2;
    const int* srcI = eidx;
    const int* dstI = eidx + E;

    // workspace layout (total ~101.2 MB)
    char* ws = (char*)d_ws;
    float* h        = (float*)(ws);                     // 10,240,000
    float* agg      = (float*)(ws + 10240000);          // 10,240,000
    float* Pd       = (float*)(ws + 20480000);          // 20,480,000
    float* Ps       = (float*)(ws + 40960000);          // 20,480,000
    _Float16* Wn    = (_Float16*)(ws + 61440000);       //    786,432
    _Float16* Wb2   = (_Float16*)(ws + 62226432);       //    196,608
    float* sums     = (float*)(ws + 62423040);          //     65,536
    unsigned* maxs  = (unsigned*)(ws + 62488576);       //     65,536
    float* gcnt     = (float*)(ws + 62554112);          //        512
    unsigned* sdS   = (unsigned*)(ws + 62554624);       //  1,280,000
    int* perm       = (int*)(ws + 63834624);            //  1,280,000
    _Float16* eaH   = (_Float16*)(ws + 65114624);       // 40,960,000 -> 106,074,624
    // sort scratch aliased into Pd (dead before first node_gemm)
    int* nodeCnt    = (int*)(ws + 20480000);
    int* cursor     = nodeCnt + N;

    prep_wn<<<(6 * 4 * 512 * 32) / 256, 256, 0, stream>>>(convWf, convWs, Wn);
    prep_wb2<<<(6 * 16384 + 255) / 256, 256, 0, stream>>>(convWf, convWs, Wb2);
    hipMemsetAsync(nodeCnt, 0, (size_t)N * 4, stream);
    hist_k<<<(E + 255) / 256, 256, 0, stream>>>(dstI, nodeCnt, E);
    scan_k<<<1, 256, 0, stream>>>(nodeCnt, cursor, N);
    scatter_k<<<(E + 255) / 256, 256, 0, stream>>>(srcI, dstI, cursor, sdS, perm, E);
    permute_ea<<<(E + 3) / 4, 256, 0, stream>>>(ea, perm, eaH, E);
    embed_k<<<(N + 1) / 2, 256, 0, stream>>>(x, embW, embB, h, N);

    const int n128 = N * 128;
    const int nblk = (N + 31) / 32;
    for (int i = 0; i < 6; ++i) {
        node_gemm<<<nblk, 256, 0, stream>>>(h, Wn + (size_t)i * 4 * 512 * 32, Pd, Ps, N);
        hipMemsetAsync(agg, 0, (size_t)n128 * 4, stream);
        edge_v4<<<E / 64, 256, 0, stream>>>(eaH, sdS,
                                            Wb2 + (size_t)i * 16384,
                                            Pd, Ps, convbf + i * 128, convbs + i * 128, agg);
        node_bn<<<(n128 + 255) / 256, 256, 0, stream>>>(
            agg, h,
            bing + i * 128, binb + i * 128, binm + i * 128, binv + i * 128,
            bog + i * 128, bob + i * 128, bom + i * 128, bov + i * 128,
            (i > 0) ? 1 : 0, n128);
    }

    hipMemsetAsync(sums, 0, 65536 + 65536 + 512, stream);
    pool_k<<<(n128 + 255) / 256, 256, 0, stream>>>(h, batch, sums, maxs, gcnt, N);
    head_k<<<128, 256, 0, stream>>>(sums, maxs, gcnt, pW, pb,
                                    f1W, f1b, f2W, f2b, f3W, f3b,
                                    d1W, d1b, d2W, d2b, (float*)d_out);
}